// Round 11
// baseline (209.980 us; speedup 1.0000x reference)
//
#include <hip/hip_runtime.h>
#include <hip/hip_bf16.h>

typedef __bf16 bf16;
typedef __bf16 bf16x4 __attribute__((ext_vector_type(4)));
typedef __bf16 bf16x8 __attribute__((ext_vector_type(8)));
typedef float f32x4 __attribute__((ext_vector_type(4)));

#define MFMA_16x16x32(A, B, C) __builtin_amdgcn_mfma_f32_16x16x32_bf16(A, B, C, 0, 0, 0)

static_assert(sizeof(bf16x8) == 16, "bf16x8 must be 16B");

__device__ __forceinline__ bf16x8 cast8(float4 lo, float4 hi) {
  return (bf16x8){(bf16)lo.x, (bf16)lo.y, (bf16)lo.z, (bf16)lo.w,
                  (bf16)hi.x, (bf16)hi.y, (bf16)hi.z, (bf16)hi.w};
}

// ---------------------------------------------------------------------------
// Kernel 0: cast + transpose weights: Wt[p][h][c] = W_p[c][h].
// ---------------------------------------------------------------------------
__global__ __launch_bounds__(256) void wtrans_kernel(
    const float* __restrict__ Wq, const float* __restrict__ Wk,
    const float* __restrict__ Wv, bf16* __restrict__ Wt)
{
  int idx = blockIdx.x * 256 + threadIdx.x;   // 3*64*1024
  int p = idx >> 16;
  int rem = idx & 65535;
  int h = rem >> 10;
  int c = rem & 1023;
  const float* W = (p == 0) ? Wq : (p == 1) ? Wk : Wv;
  Wt[idx] = (bf16)W[c * 64 + h];
}

// ---------------------------------------------------------------------------
// Kernel 1: projections — MAX-OCCUPANCY free-running streaming GEMM.
// Post-R10 diagnosis: every prior variant was capped <=16 waves/CU (grid,
// LDS, or barriers), and the compiler deletes software prefetch regardless
// (VGPR 48-88 across rounds). m13's 6.3 TB/s copy = at-use loads at 32
// waves/CU: MLP comes from RESIDENT WAVES. This kernel: one task =
// (16-row strip, one of Q/K/V) PER WAVE, full K=1024. 6144 tasks = 1536
// blocks x 4 waves = 24 waves/CU. ZERO LDS, ZERO barriers, ZERO prefetch:
// per 32-k chunk, 2 float4 A-loads + 4 bf16x8 B-loads (L2-resident Wt,
// 128KB/matrix) issue back-to-back -> ~6 wave-instrs naturally in flight
// x 24 waves >> the ~22KB/CU needed to cover HBM latency at full rate.
// __launch_bounds__(256,8) pins VGPR <= 64 (the 8-waves/SIMD step).
// Tasks 3t..3t+2 (Q,K,V of one strip) land in the same block: the k-strip
// is read once and serves both K- and V-waves via L1/L2.
// ---------------------------------------------------------------------------
__global__ __launch_bounds__(256, 8) void proj_kernel(
    const float* __restrict__ qin, const float* __restrict__ kin,
    const bf16* __restrict__ Wt,
    bf16* __restrict__ Qb, bf16* __restrict__ Kb, bf16* __restrict__ Vtb)
{
  const int tid = threadIdx.x;
  const int lane = tid & 63;
  const int w = tid >> 6;
  const int g = lane >> 4;
  const int r = lane & 15;

  const int task = blockIdx.x * 4 + w;       // 0..6143
  const int strip = task / 3;                // 0..2047  (16 output rows)
  const int mat = task - strip * 3;          // 0:Q 1:K 2:V

  const float* A = (mat == 0) ? qin : kin;
  // A fragment pointer: lane (g,r) -> row strip*16+r, k-slice g*8..g*8+7
  const float* ap = A + ((size_t)strip * 16 + r) * 1024 + g * 8;
  // B fragment pointer: W-row (= output col) cf*16+r, same k-slice
  const bf16* bp = Wt + (size_t)mat * 65536 + (size_t)r * 1024 + g * 8;

  f32x4 acc[4];
  #pragma unroll
  for (int cf = 0; cf < 4; cf++) acc[cf] = (f32x4){0.f, 0.f, 0.f, 0.f};

  // 32 chunks of K=32. At-use loads; unroll lets the scheduler keep a few
  // chunks' loads in flight within the 64-VGPR budget.
  #pragma unroll 4
  for (int c = 0; c < 32; ++c) {
    float4 a0 = *(const float4*)(ap + c * 32);
    float4 a1 = *(const float4*)(ap + c * 32 + 4);
    bf16x8 af = cast8(a0, a1);
    #pragma unroll
    for (int cf = 0; cf < 4; cf++) {
      bf16x8 bfr = *(const bf16x8*)(bp + (size_t)cf * 16384 + c * 32);
      acc[cf] = MFMA_16x16x32(af, bfr, acc[cf]);
    }
  }

  // --- epilogue: C/D layout row=(l>>4)*4+j, col=l&15 ---
  if (mat < 2) {
    bf16* O = (mat == 0) ? Qb : Kb;
    #pragma unroll
    for (int cf = 0; cf < 4; cf++) {
      #pragma unroll
      for (int jj = 0; jj < 4; jj++) {
        int rg = strip * 16 + g * 4 + jj;
        O[(size_t)rg * 64 + cf * 16 + r] = (bf16)acc[cf][jj];
      }
    }
  } else {
    // V: transposed store Vt[b][h][t]; 4 consecutive-t bf16 packed -> 8B
    int bb = (strip * 16) >> 11;
    int t0 = (strip * 16 + g * 4) & 2047;
    #pragma unroll
    for (int cf = 0; cf < 4; cf++) {
      bf16x4 v = (bf16x4){(bf16)acc[cf][0], (bf16)acc[cf][1],
                          (bf16)acc[cf][2], (bf16)acc[cf][3]};
      *(bf16x4*)&Vtb[((size_t)(bb * 64 + cf * 16 + r)) * 2048 + t0] = v;
    }
  }
}

// ---------------------------------------------------------------------------
// Kernel 2: causal flash attention (unchanged).
// ---------------------------------------------------------------------------
__global__ __launch_bounds__(256) void attn_kernel(
    const bf16* __restrict__ Qb, const bf16* __restrict__ Kb,
    const bf16* __restrict__ Vtb, float* __restrict__ out)
{
  const int qt = (int)(gridDim.x - 1 - blockIdx.x);   // heavy blocks first
  const int b = blockIdx.y;
  const int tid = threadIdx.x;
  const int lane = tid & 63;
  const int w = tid >> 6;
  const int g = lane >> 4;
  const int r = lane & 15;

  __shared__ __align__(16) bf16 Ks[64][80];
  __shared__ __align__(16) bf16 Vs[64][80];
  __shared__ __align__(16) bf16 Ps[4][16][80];

  const int q0 = qt * 64 + w * 16;
  const bf16* qp = Qb + (size_t)(b * 2048 + q0 + r) * 64 + g * 8;
  const bf16x8 qf0 = *(const bf16x8*)qp;
  const bf16x8 qf1 = *(const bf16x8*)(qp + 32);

  f32x4 acc_o[4];
  #pragma unroll
  for (int hf = 0; hf < 4; hf++) acc_o[hf] = (f32x4){0.f, 0.f, 0.f, 0.f};
  float m_r[4] = {-1e30f, -1e30f, -1e30f, -1e30f};
  float l_r[4] = {0.f, 0.f, 0.f, 0.f};
  const float scale = 0.03125f;   // 1/sqrt(1024)

  const int sh = tid >> 2;
  const int sc = (tid & 3) * 16;

  for (int kv = 0; kv <= qt; kv++) {
    {
      const bf16* kp = Kb + (size_t)(b * 2048 + kv * 64 + sh) * 64 + sc;
      *(bf16x8*)&Ks[sh][sc]     = *(const bf16x8*)kp;
      *(bf16x8*)&Ks[sh][sc + 8] = *(const bf16x8*)(kp + 8);
      const bf16* vp = Vtb + (size_t)(b * 64 + sh) * 2048 + kv * 64 + sc;
      *(bf16x8*)&Vs[sh][sc]     = *(const bf16x8*)vp;
      *(bf16x8*)&Vs[sh][sc + 8] = *(const bf16x8*)(vp + 8);
    }
    __syncthreads();

    f32x4 s[4];
    #pragma unroll
    for (int cf = 0; cf < 4; cf++) {
      bf16x8 kf0 = *(const bf16x8*)&Ks[cf * 16 + r][g * 8];
      bf16x8 kf1 = *(const bf16x8*)&Ks[cf * 16 + r][32 + g * 8];
      f32x4 t = (f32x4){0.f, 0.f, 0.f, 0.f};
      t = MFMA_16x16x32(qf0, kf0, t);
      t = MFMA_16x16x32(qf1, kf1, t);
      s[cf] = t;
    }

    const bool diag = (kv == qt);
    float pm[4] = {-1e30f, -1e30f, -1e30f, -1e30f};
    #pragma unroll
    for (int cf = 0; cf < 4; cf++) {
      #pragma unroll
      for (int j = 0; j < 4; j++) {
        float v = s[cf][j] * scale;
        if (diag && (cf * 16 + r) > (w * 16 + g * 4 + j)) v = -1e30f;
        s[cf][j] = v;
        pm[j] = fmaxf(pm[j], v);
      }
    }
    #pragma unroll
    for (int j = 0; j < 4; j++) {
      #pragma unroll
      for (int msk = 1; msk < 16; msk <<= 1)
        pm[j] = fmaxf(pm[j], __shfl_xor(pm[j], msk, 64));
    }
    float corr[4];
    #pragma unroll
    for (int j = 0; j < 4; j++) {
      float mn = fmaxf(m_r[j], pm[j]);
      corr[j] = __expf(m_r[j] - mn);
      m_r[j] = mn;
    }
    float rs[4] = {0.f, 0.f, 0.f, 0.f};
    #pragma unroll
    for (int cf = 0; cf < 4; cf++) {
      #pragma unroll
      for (int j = 0; j < 4; j++) {
        float pv = __expf(s[cf][j] - m_r[j]);
        s[cf][j] = pv;
        rs[j] += pv;
      }
    }
    #pragma unroll
    for (int j = 0; j < 4; j++) {
      #pragma unroll
      for (int msk = 1; msk < 16; msk <<= 1)
        rs[j] += __shfl_xor(rs[j], msk, 64);
      l_r[j] = l_r[j] * corr[j] + rs[j];
    }
    #pragma unroll
    for (int hf = 0; hf < 4; hf++)
      #pragma unroll
      for (int j = 0; j < 4; j++)
        acc_o[hf][j] *= corr[j];

    #pragma unroll
    for (int cf = 0; cf < 4; cf++)
      #pragma unroll
      for (int j = 0; j < 4; j++)
        Ps[w][g * 4 + j][cf * 16 + r] = (bf16)s[cf][j];

    __syncthreads();

    #pragma unroll
    for (int ss = 0; ss < 2; ss++) {
      bf16x8 pf = *(const bf16x8*)&Ps[w][r][ss * 32 + g * 8];
      #pragma unroll
      for (int hf = 0; hf < 4; hf++) {
        bf16x8 vf = *(const bf16x8*)&Vs[hf * 16 + r][ss * 32 + g * 8];
        acc_o[hf] = MFMA_16x16x32(pf, vf, acc_o[hf]);
      }
    }
    __syncthreads();
  }

  float inv[4];
  #pragma unroll
  for (int j = 0; j < 4; j++) inv[j] = 1.0f / l_r[j];
  const size_t ob = (size_t)(b * 2048 + q0) * 64;
  #pragma unroll
  for (int hf = 0; hf < 4; hf++)
    #pragma unroll
    for (int j = 0; j < 4; j++)
      out[ob + (size_t)(g * 4 + j) * 64 + hf * 16 + r] = acc_o[hf][j] * inv[j];
}

// ---------------------------------------------------------------------------
extern "C" void kernel_launch(void* const* d_in, const int* in_sizes, int n_in,
                              void* d_out, int out_size, void* d_ws, size_t ws_size,
                              hipStream_t stream)
{
  const float* q  = (const float*)d_in[0];
  const float* k  = (const float*)d_in[1];
  const float* Wq = (const float*)d_in[2];
  const float* Wk = (const float*)d_in[3];
  const float* Wv = (const float*)d_in[4];
  float* out = (float*)d_out;

  char* ws = (char*)d_ws;
  bf16* Qb  = (bf16*)(ws);                      // [16*2048][64] bf16, 4MB
  bf16* Kb  = (bf16*)(ws + (4u << 20));         // [16*2048][64] bf16, 4MB
  bf16* Vtb = (bf16*)(ws + (8u << 20));         // [16][64][2048] bf16, 4MB
  bf16* Wt  = (bf16*)(ws + (12u << 20));        // [3][64][1024] bf16, 384KB

  hipLaunchKernelGGL(wtrans_kernel, dim3(768), dim3(256), 0, stream,
                     Wq, Wk, Wv, Wt);
  hipLaunchKernelGGL(proj_kernel, dim3(1536), dim3(256), 0, stream,
                     q, k, Wt, Qb, Kb, Vtb);
  hipLaunchKernelGGL(attn_kernel, dim3(32, 16), dim3(256), 0, stream,
                     Qb, Kb, Vtb, out);
}

// Round 12
// 125.608 us; speedup vs baseline: 1.6717x; 1.6717x over previous
//
#include <hip/hip_runtime.h>
#include <hip/hip_bf16.h>

typedef __bf16 bf16;
typedef __bf16 bf16x4 __attribute__((ext_vector_type(4)));
typedef __bf16 bf16x8 __attribute__((ext_vector_type(8)));
typedef float f32x4 __attribute__((ext_vector_type(4)));

#define MFMA_16x16x32(A, B, C) __builtin_amdgcn_mfma_f32_16x16x32_bf16(A, B, C, 0, 0, 0)

static_assert(sizeof(bf16x8) == 16, "bf16x8 must be 16B");

// ---------------------------------------------------------------------------
// Kernel 0: cast + transpose weights: Wt[p][h][c] = W_p[c][h].
// ---------------------------------------------------------------------------
__global__ __launch_bounds__(256) void wtrans_kernel(
    const float* __restrict__ Wq, const float* __restrict__ Wk,
    const float* __restrict__ Wv, bf16* __restrict__ Wt)
{
  int idx = blockIdx.x * 256 + threadIdx.x;   // 3*64*1024
  int p = idx >> 16;
  int rem = idx & 65535;
  int h = rem >> 10;
  int c = rem & 1023;
  const float* W = (p == 0) ? Wq : (p == 1) ? Wk : Wv;
  Wt[idx] = (bf16)W[c * 64 + h];
}

// ---------------------------------------------------------------------------
// Kernel 1: projections — minimal-traffic + 16 waves/CU (the untested
// quadrant of the delivered-bytes model).
// 256 blocks x 1024 threads (16 waves), 1 block/CU, ~148 KB dynamic LDS.
//  bid <128 : Q-family. Wq (128 KB) LDS-resident; wave w computes strip
//             bid*16+w (16 rows, full K) — EXACTLY 1 strip/wave.
//  bid>=128 : KV-family. k read ONCE; Wk+Wv staged per k-phase (4 phases
//             x 64 KB, 2 barriers each); acc for K AND V in registers.
// A loads are FULL-LINE (lane rl=lane>>2 reads 16B slot l4 of each 64B
// line -> 1 line-touch per line), redistributed to the MFMA fragment
// layout via a PER-WAVE bf16 LDS stage [16][40] (80B rows: 16B-aligned
// b128 reads; same-wave DS ops are in-order -> no barrier).
// Delivered bytes ~= q128 + k128 + W-stage 48 + stores 12 = 316 MB
// -> 50us floor at the 6.3 TB/s delivery ceiling; 16 waves x ~2KB
// at-use in-flight = 32KB/CU covers HBM latency (R10-kernel had only 8).
// ---------------------------------------------------------------------------
__global__ __launch_bounds__(1024, 4) void proj_kernel(
    const float* __restrict__ qin, const float* __restrict__ kin,
    const bf16* __restrict__ Wt,
    bf16* __restrict__ Qb, bf16* __restrict__ Kb, bf16* __restrict__ Vtb)
{
  extern __shared__ __align__(16) bf16 lds[];
  // layout: [0 .. 65535]   B-region (Q: [64][1024]; KV: 2 x [64][256] tiles)
  //         [65536 .. ]    16 waves x [16][40] bf16 A-stage
  const int tid = threadIdx.x;
  const int lane = tid & 63;
  const int w = tid >> 6;          // wave 0..15
  const int g = lane >> 4;
  const int r = lane & 15;
  const int rl = lane >> 2;        // full-line load: row 0..15
  const int l4 = lane & 3;         // full-line load: 16B slot in line

  bf16* const stageW = lds + 65536 + w * 640;   // [16][40] bf16 per wave

  const int bid = blockIdx.x;
  const bool isQ = (bid < 128);
  const int fbid = isQ ? bid : bid - 128;
  const int strip = fbid * 16 + w;              // 0..2047
  const float* A = isQ ? qin : kin;
  const float* ap = A + (size_t)strip * 16 * 1024;

  f32x4 acc0[4], acc1[4];
  #pragma unroll
  for (int cf = 0; cf < 4; cf++) {
    acc0[cf] = (f32x4){0.f, 0.f, 0.f, 0.f};
    acc1[cf] = (f32x4){0.f, 0.f, 0.f, 0.f};
  }

  // full-line A load for chunk c (32 floats/row), convert, redistribute,
  // return this lane's MFMA A-fragment (row r, k-slice g*8..g*8+7).
  auto afrag = [&](int c) -> bf16x8 {
    const float* rowp = ap + (size_t)rl * 1024 + c * 32 + l4 * 4;
    float4 a0 = *(const float4*)(rowp);        // line0: floats 0..15
    float4 a1 = *(const float4*)(rowp + 16);   // line1: floats 16..31
    bf16x4 w0 = (bf16x4){(bf16)a0.x, (bf16)a0.y, (bf16)a0.z, (bf16)a0.w};
    bf16x4 w1 = (bf16x4){(bf16)a1.x, (bf16)a1.y, (bf16)a1.z, (bf16)a1.w};
    *(bf16x4*)&stageW[rl * 40 + l4 * 4] = w0;        // cols l4*4..+3
    *(bf16x4*)&stageW[rl * 40 + 16 + l4 * 4] = w1;   // cols 16+l4*4..+3
    return *(const bf16x8*)&stageW[r * 40 + g * 8];  // in-order DS: safe
  };

  if (isQ) {
    // --- stage Wq [64][1024] once, chunk-swizzled ---
    #pragma unroll
    for (int i = 0; i < 8; ++i) {
      int cid = i * 1024 + tid;            // 16B chunk, 0..8191
      int row = cid >> 7, ch = cid & 127;
      int pch = ch ^ (row & 7);
      *(bf16x8*)&lds[row * 1024 + pch * 8] =
          *(const bf16x8*)(Wt + (size_t)row * 1024 + ch * 8);
    }
    __syncthreads();

    #pragma unroll 2
    for (int c = 0; c < 32; ++c) {
      bf16x8 af = afrag(c);
      #pragma unroll
      for (int cf = 0; cf < 4; cf++) {
        int rw = cf * 16 + r;
        int pch = (4 * c + g) ^ (rw & 7);
        bf16x8 bfr = *(const bf16x8*)&lds[rw * 1024 + pch * 8];
        acc0[cf] = MFMA_16x16x32(af, bfr, acc0[cf]);
      }
    }

    #pragma unroll
    for (int cf = 0; cf < 4; cf++)
      #pragma unroll
      for (int jj = 0; jj < 4; jj++) {
        int rg = strip * 16 + g * 4 + jj;
        Qb[(size_t)rg * 64 + cf * 16 + r] = (bf16)acc0[cf][jj];
      }
  } else {
    // --- KV: 4 k-phases; per phase stage Wk,Wv tiles [64][256] ---
    for (int p = 0; p < 4; ++p) {
      __syncthreads();   // previous phase's reads done (WAR)
      #pragma unroll
      for (int i = 0; i < 2; ++i) {
        int cid = i * 1024 + tid;          // 0..2047 chunks per tile
        int row = cid >> 5, ch = cid & 31;
        int pch = ch ^ (row & 7);
        *(bf16x8*)&lds[row * 256 + pch * 8] =
            *(const bf16x8*)(Wt + 65536 + (size_t)row * 1024 + p * 256 + ch * 8);
        *(bf16x8*)&lds[16384 + row * 256 + pch * 8] =
            *(const bf16x8*)(Wt + 2 * 65536 + (size_t)row * 1024 + p * 256 + ch * 8);
      }
      __syncthreads();

      #pragma unroll 2
      for (int cl = 0; cl < 8; ++cl) {
        bf16x8 af = afrag(p * 8 + cl);
        #pragma unroll
        for (int cf = 0; cf < 4; cf++) {
          int rw = cf * 16 + r;
          int pch = (4 * cl + g) ^ (rw & 7);
          bf16x8 b0 = *(const bf16x8*)&lds[rw * 256 + pch * 8];
          acc0[cf] = MFMA_16x16x32(af, b0, acc0[cf]);
          bf16x8 b1 = *(const bf16x8*)&lds[16384 + rw * 256 + pch * 8];
          acc1[cf] = MFMA_16x16x32(af, b1, acc1[cf]);
        }
      }
    }

    // K row-major; V transposed Vt[b][h][t] (4 consecutive-t packed -> 8B)
    #pragma unroll
    for (int cf = 0; cf < 4; cf++)
      #pragma unroll
      for (int jj = 0; jj < 4; jj++) {
        int rg = strip * 16 + g * 4 + jj;
        Kb[(size_t)rg * 64 + cf * 16 + r] = (bf16)acc0[cf][jj];
      }
    int bb = (strip * 16) >> 11;
    int t0 = (strip * 16 + g * 4) & 2047;
    #pragma unroll
    for (int cf = 0; cf < 4; cf++) {
      bf16x4 v = (bf16x4){(bf16)acc1[cf][0], (bf16)acc1[cf][1],
                          (bf16)acc1[cf][2], (bf16)acc1[cf][3]};
      *(bf16x4*)&Vtb[((size_t)(bb * 64 + cf * 16 + r)) * 2048 + t0] = v;
    }
  }
}

// ---------------------------------------------------------------------------
// Kernel 2: causal flash attention (unchanged).
// ---------------------------------------------------------------------------
__global__ __launch_bounds__(256) void attn_kernel(
    const bf16* __restrict__ Qb, const bf16* __restrict__ Kb,
    const bf16* __restrict__ Vtb, float* __restrict__ out)
{
  const int qt = (int)(gridDim.x - 1 - blockIdx.x);   // heavy blocks first
  const int b = blockIdx.y;
  const int tid = threadIdx.x;
  const int lane = tid & 63;
  const int w = tid >> 6;
  const int g = lane >> 4;
  const int r = lane & 15;

  __shared__ __align__(16) bf16 Ks[64][80];
  __shared__ __align__(16) bf16 Vs[64][80];
  __shared__ __align__(16) bf16 Ps[4][16][80];

  const int q0 = qt * 64 + w * 16;
  const bf16* qp = Qb + (size_t)(b * 2048 + q0 + r) * 64 + g * 8;
  const bf16x8 qf0 = *(const bf16x8*)qp;
  const bf16x8 qf1 = *(const bf16x8*)(qp + 32);

  f32x4 acc_o[4];
  #pragma unroll
  for (int hf = 0; hf < 4; hf++) acc_o[hf] = (f32x4){0.f, 0.f, 0.f, 0.f};
  float m_r[4] = {-1e30f, -1e30f, -1e30f, -1e30f};
  float l_r[4] = {0.f, 0.f, 0.f, 0.f};
  const float scale = 0.03125f;   // 1/sqrt(1024)

  const int sh = tid >> 2;
  const int sc = (tid & 3) * 16;

  for (int kv = 0; kv <= qt; kv++) {
    {
      const bf16* kp = Kb + (size_t)(b * 2048 + kv * 64 + sh) * 64 + sc;
      *(bf16x8*)&Ks[sh][sc]     = *(const bf16x8*)kp;
      *(bf16x8*)&Ks[sh][sc + 8] = *(const bf16x8*)(kp + 8);
      const bf16* vp = Vtb + (size_t)(b * 64 + sh) * 2048 + kv * 64 + sc;
      *(bf16x8*)&Vs[sh][sc]     = *(const bf16x8*)vp;
      *(bf16x8*)&Vs[sh][sc + 8] = *(const bf16x8*)(vp + 8);
    }
    __syncthreads();

    f32x4 s[4];
    #pragma unroll
    for (int cf = 0; cf < 4; cf++) {
      bf16x8 kf0 = *(const bf16x8*)&Ks[cf * 16 + r][g * 8];
      bf16x8 kf1 = *(const bf16x8*)&Ks[cf * 16 + r][32 + g * 8];
      f32x4 t = (f32x4){0.f, 0.f, 0.f, 0.f};
      t = MFMA_16x16x32(qf0, kf0, t);
      t = MFMA_16x16x32(qf1, kf1, t);
      s[cf] = t;
    }

    const bool diag = (kv == qt);
    float pm[4] = {-1e30f, -1e30f, -1e30f, -1e30f};
    #pragma unroll
    for (int cf = 0; cf < 4; cf++) {
      #pragma unroll
      for (int j = 0; j < 4; j++) {
        float v = s[cf][j] * scale;
        if (diag && (cf * 16 + r) > (w * 16 + g * 4 + j)) v = -1e30f;
        s[cf][j] = v;
        pm[j] = fmaxf(pm[j], v);
      }
    }
    #pragma unroll
    for (int j = 0; j < 4; j++) {
      #pragma unroll
      for (int msk = 1; msk < 16; msk <<= 1)
        pm[j] = fmaxf(pm[j], __shfl_xor(pm[j], msk, 64));
    }
    float corr[4];
    #pragma unroll
    for (int j = 0; j < 4; j++) {
      float mn = fmaxf(m_r[j], pm[j]);
      corr[j] = __expf(m_r[j] - mn);
      m_r[j] = mn;
    }
    float rs[4] = {0.f, 0.f, 0.f, 0.f};
    #pragma unroll
    for (int cf = 0; cf < 4; cf++) {
      #pragma unroll
      for (int j = 0; j < 4; j++) {
        float pv = __expf(s[cf][j] - m_r[j]);
        s[cf][j] = pv;
        rs[j] += pv;
      }
    }
    #pragma unroll
    for (int j = 0; j < 4; j++) {
      #pragma unroll
      for (int msk = 1; msk < 16; msk <<= 1)
        rs[j] += __shfl_xor(rs[j], msk, 64);
      l_r[j] = l_r[j] * corr[j] + rs[j];
    }
    #pragma unroll
    for (int hf = 0; hf < 4; hf++)
      #pragma unroll
      for (int j = 0; j < 4; j++)
        acc_o[hf][j] *= corr[j];

    #pragma unroll
    for (int cf = 0; cf < 4; cf++)
      #pragma unroll
      for (int j = 0; j < 4; j++)
        Ps[w][g * 4 + j][cf * 16 + r] = (bf16)s[cf][j];

    __syncthreads();

    #pragma unroll
    for (int ss = 0; ss < 2; ss++) {
      bf16x8 pf = *(const bf16x8*)&Ps[w][r][ss * 32 + g * 8];
      #pragma unroll
      for (int hf = 0; hf < 4; hf++) {
        bf16x8 vf = *(const bf16x8*)&Vs[hf * 16 + r][ss * 32 + g * 8];
        acc_o[hf] = MFMA_16x16x32(pf, vf, acc_o[hf]);
      }
    }
    __syncthreads();
  }

  float inv[4];
  #pragma unroll
  for (int j = 0; j < 4; j++) inv[j] = 1.0f / l_r[j];
  const size_t ob = (size_t)(b * 2048 + q0) * 64;
  #pragma unroll
  for (int hf = 0; hf < 4; hf++)
    #pragma unroll
    for (int j = 0; j < 4; j++)
      out[ob + (size_t)(g * 4 + j) * 64 + hf * 16 + r] = acc_o[hf][j] * inv[j];
}

// ---------------------------------------------------------------------------
extern "C" void kernel_launch(void* const* d_in, const int* in_sizes, int n_in,
                              void* d_out, int out_size, void* d_ws, size_t ws_size,
                              hipStream_t stream)
{
  const float* q  = (const float*)d_in[0];
  const float* k  = (const float*)d_in[1];
  const float* Wq = (const float*)d_in[2];
  const float* Wk = (const float*)d_in[3];
  const float* Wv = (const float*)d_in[4];
  float* out = (float*)d_out;

  char* ws = (char*)d_ws;
  bf16* Qb  = (bf16*)(ws);                      // [16*2048][64] bf16, 4MB
  bf16* Kb  = (bf16*)(ws + (4u << 20));         // [16*2048][64] bf16, 4MB
  bf16* Vtb = (bf16*)(ws + (8u << 20));         // [16][64][2048] bf16, 4MB
  bf16* Wt  = (bf16*)(ws + (12u << 20));        // [3][64][1024] bf16, 384KB

  hipLaunchKernelGGL(wtrans_kernel, dim3(768), dim3(256), 0, stream,
                     Wq, Wk, Wv, Wt);
  // dynamic LDS: 131072 (B region) + 16 waves * 640 bf16 * 2B = 151552 B
  hipLaunchKernelGGL(proj_kernel, dim3(256), dim3(1024), 151552, stream,
                     q, k, Wt, Qb, Kb, Vtb);
  hipLaunchKernelGGL(attn_kernel, dim3(32, 16), dim3(256), 0, stream,
                     Qb, Kb, Vtb, out);
}